// Round 9
// baseline (188.229 us; speedup 1.0000x reference)
//
#include <hip/hip_runtime.h>
#include <hip/hip_bf16.h>

// MultiDilatelocalAttention, round 9: tri-buffered depth-2 GEMM pipeline.
// Stage tile t+2 at iter t (loads span TWO compute windows); gate tile t with
// counted vmcnt(8) (t+1/t+2 loads stay in flight); s_setprio around MFMA
// cluster. conv_all / attention / XCD remap unchanged from round 8.

#define NTOK 50176
#define ROWQKV 1152
#define CDIM 384

typedef _Float16 half2v __attribute__((ext_vector_type(2)));
typedef _Float16 half8 __attribute__((ext_vector_type(8)));
typedef float floatx4 __attribute__((ext_vector_type(4)));

typedef __attribute__((address_space(1))) const unsigned int GU32;
typedef __attribute__((address_space(3))) unsigned int LU32;

// ---------------- fused fp32 -> fp16 conversion: x, w_qkv, w_proj ----------------
#define N_X4 (NTOK * CDIM / 4)
#define N_Q4 (ROWQKV * CDIM / 4)
#define N_P4 (CDIM * CDIM / 4)

__global__ __launch_bounds__(256) void conv_all(const float* __restrict__ x,
                                                const float* __restrict__ wq,
                                                const float* __restrict__ wp,
                                                _Float16* __restrict__ xh,
                                                _Float16* __restrict__ wqh,
                                                _Float16* __restrict__ wph) {
  const int total = N_X4 + N_Q4 + N_P4;
  int i = blockIdx.x * 256 + threadIdx.x;
  const int stride = gridDim.x * 256;
  for (; i < total; i += stride) {
    const float* src;
    _Float16* dst;
    int k;
    if (i < N_X4) { src = x; dst = xh; k = i; }
    else if (i < N_X4 + N_Q4) { src = wq; dst = wqh; k = i - N_X4; }
    else { src = wp; dst = wph; k = i - N_X4 - N_Q4; }
    float4 v = ((const float4*)src)[k];
    union { _Float16 h[4]; uint2 u; } o;
    o.h[0] = (_Float16)v.x; o.h[1] = (_Float16)v.y;
    o.h[2] = (_Float16)v.z; o.h[3] = (_Float16)v.w;
    ((uint2*)dst)[k] = o.u;
  }
}

// ---------------- f16 MFMA GEMM, tri-buffer depth-2: C = A * B^T ----------------
// 128x128 tile, BK=32, 256 threads (4 waves 2x2), 4x4 frags of 16x16x32 per wave.
// Iter t: stage tile t+2 into buf (t+2)%3; gate tile t with vmcnt(8) (8 newer
// loads stay in flight); raw barriers only; setprio(1) around the MFMA cluster.
// 1D grid, XCD-chunked remap. LDS = 3 bufs x (8KB A + 8KB B) = 48KB.
template <bool HALF_OUT>
__global__ __launch_bounds__(256) void gemm3(const _Float16* __restrict__ A,
                                             const _Float16* __restrict__ B,
                                             const float* __restrict__ bias,
                                             void* __restrict__ Cout,
                                             int N, int K) {
  __shared__ _Float16 As[3][128 * 32];
  __shared__ _Float16 Bs[3][128 * 32];
  const int tid = threadIdx.x;
  const int lane = tid & 63;
  const int wv = tid >> 6;
  const int wr = wv >> 1, wc = wv & 1;

  const int nN = N >> 7;
  const int p = blockIdx.x;
  const int l = (p & 7) * (gridDim.x >> 3) + (p >> 3);
  const size_t row0 = (size_t)(l / nN) * 128;
  const int col0 = (l % nN) * 128;
  const int NT = K / 32;

  const int srow = tid >> 2;
  const int gslot = (tid & 3) ^ ((srow >> 1) & 3);  // swizzled source slot
  const _Float16* Abase = A + (row0 + srow) * (size_t)K + gslot * 8;
  const _Float16* Bbase = B + ((size_t)(col0 + srow)) * (size_t)K + gslot * 8;
  char* AsB = (char*)As;
  char* BsB = (char*)Bs;

  auto stage = [&](int k0, int buf) {
    __builtin_amdgcn_global_load_lds((GU32*)(Abase + k0),
                                     (LU32*)(AsB + buf * 8192 + tid * 16), 16, 0, 0);
    __builtin_amdgcn_global_load_lds((GU32*)(Abase + (size_t)64 * K + k0),
                                     (LU32*)(AsB + buf * 8192 + tid * 16 + 4096), 16, 0, 0);
    __builtin_amdgcn_global_load_lds((GU32*)(Bbase + k0),
                                     (LU32*)(BsB + buf * 8192 + tid * 16), 16, 0, 0);
    __builtin_amdgcn_global_load_lds((GU32*)(Bbase + (size_t)64 * K + k0),
                                     (LU32*)(BsB + buf * 8192 + tid * 16 + 4096), 16, 0, 0);
  };

  const int fr = lane & 15;
  const int fq = lane >> 4;
  const int rpos = (fq ^ ((fr >> 1) & 3)) * 8;

  floatx4 acc[4][4];
#pragma unroll
  for (int i = 0; i < 4; ++i)
#pragma unroll
    for (int j = 0; j < 4; ++j) acc[i][j] = (floatx4){0.f, 0.f, 0.f, 0.f};

  // prologue: two tiles in flight, no drain
  stage(0, 0);
  stage(32, 1);

  int cur = 0;
  for (int t = 0; t < NT; ++t) {
    // depth-2 prefetch + counted gate for tile t
    if (t + 2 < NT) {
      stage((t + 2) * 32, (t + 2) % 3);
      asm volatile("s_waitcnt vmcnt(8)" ::: "memory");   // t+1, t+2 stay in flight
    } else if (t + 1 < NT) {
      asm volatile("s_waitcnt vmcnt(4)" ::: "memory");   // t+1 stays in flight
    } else {
      asm volatile("s_waitcnt vmcnt(0)" ::: "memory");
    }
    __builtin_amdgcn_s_barrier();          // tile t landed for ALL threads
    __builtin_amdgcn_sched_barrier(0);     // no hoisting of ds_reads above

    half8 af[4], bf[4];
#pragma unroll
    for (int f = 0; f < 4; ++f) {
      af[f] = *(const half8*)&As[cur][(wr * 64 + f * 16 + fr) * 32 + rpos];
      bf[f] = *(const half8*)&Bs[cur][(wc * 64 + f * 16 + fr) * 32 + rpos];
    }
    __builtin_amdgcn_s_setprio(1);
#pragma unroll
    for (int i = 0; i < 4; ++i)
#pragma unroll
      for (int j = 0; j < 4; ++j)
        acc[i][j] = __builtin_amdgcn_mfma_f32_16x16x32_f16(af[i], bf[j], acc[i][j], 0, 0, 0);
    __builtin_amdgcn_s_setprio(0);
    __builtin_amdgcn_sched_barrier(0);     // MFMAs (and their reads) stay above
    __builtin_amdgcn_s_barrier();          // buf cur free for tile t+3's DMA
    cur = (cur == 2) ? 0 : cur + 1;
  }

  const int crow = wr * 64 + (lane >> 4) * 4;
  const int ccol = wc * 64 + (lane & 15);
#pragma unroll
  for (int fm = 0; fm < 4; ++fm) {
#pragma unroll
    for (int fn = 0; fn < 4; ++fn) {
      const size_t r0 = (row0 + crow + fm * 16) * (size_t)N + col0 + ccol + fn * 16;
      if (HALF_OUT) {
        _Float16* C = (_Float16*)Cout;
#pragma unroll
        for (int j = 0; j < 4; ++j) C[r0 + (size_t)j * N] = (_Float16)acc[fm][fn][j];
      } else {
        float* C = (float*)Cout;
        const float bz = bias[col0 + ccol + fn * 16];
#pragma unroll
        for (int j = 0; j < 4; ++j) C[r0 + (size_t)j * N] = acc[fm][fn][j] + bz;
      }
    }
  }
}

// ---------------- Local attention: one thread per (token, head) ----------------
__global__ __launch_bounds__(256) void attn_kernel(const _Float16* __restrict__ qkv,
                                                   _Float16* __restrict__ y) {
  const int idx = blockIdx.x * 256 + threadIdx.x;  // token*12 + head
  const int head = idx % 12;
  const int token = idx / 12;
  const int branch = head >> 2;
  const int dil = branch + 1;
  const int cbase = branch * 128 + (head & 3) * 32;
  const int xx = token % 56;
  const int yy = (token / 56) % 56;
  const int bimg = token / 3136;
  const float scale = 0.17677669529663687f;  // 1/sqrt(32)

  const _Float16* qp = qkv + (size_t)token * ROWQKV + cbase;
  half2v qh[16];
  *(half8*)&qh[0] = *(const half8*)(qp);
  *(half8*)&qh[4] = *(const half8*)(qp + 8);
  *(half8*)&qh[8] = *(const half8*)(qp + 16);
  *(half8*)&qh[12] = *(const half8*)(qp + 24);

  const size_t nbase = (size_t)bimg * 3136;

  float l[9];
#pragma unroll
  for (int j = 0; j < 9; ++j) {
    const int ny = yy + (j / 3 - 1) * dil;
    const int nx = xx + (j % 3 - 1) * dil;
    float d = 0.f;
    if ((unsigned)ny < 56u && (unsigned)nx < 56u) {
      const _Float16* kp = qkv + (nbase + ny * 56 + nx) * ROWQKV + 384 + cbase;
      half2v kh[16];
      *(half8*)&kh[0] = *(const half8*)(kp);
      *(half8*)&kh[4] = *(const half8*)(kp + 8);
      *(half8*)&kh[8] = *(const half8*)(kp + 16);
      *(half8*)&kh[12] = *(const half8*)(kp + 24);
#if __has_builtin(__builtin_amdgcn_fdot2)
#pragma unroll
      for (int c = 0; c < 16; ++c) d = __builtin_amdgcn_fdot2(qh[c], kh[c], d, false);
#else
#pragma unroll
      for (int c = 0; c < 16; ++c)
        d += (float)qh[c][0] * (float)kh[c][0] + (float)qh[c][1] * (float)kh[c][1];
#endif
    }
    l[j] = d * scale;
  }

  float m = l[0];
#pragma unroll
  for (int j = 1; j < 9; ++j) m = fmaxf(m, l[j]);
  float s = 0.f;
#pragma unroll
  for (int j = 0; j < 9; ++j) { l[j] = expf(l[j] - m); s += l[j]; }
  const float rs = 1.f / s;

  float out[32];
#pragma unroll
  for (int c = 0; c < 32; ++c) out[c] = 0.f;
#pragma unroll
  for (int j = 0; j < 9; ++j) {
    const int ny = yy + (j / 3 - 1) * dil;
    const int nx = xx + (j % 3 - 1) * dil;
    if ((unsigned)ny < 56u && (unsigned)nx < 56u) {
      const _Float16* vp = qkv + (nbase + ny * 56 + nx) * ROWQKV + 768 + cbase;
      half8 vh[4];
      vh[0] = *(const half8*)(vp);
      vh[1] = *(const half8*)(vp + 8);
      vh[2] = *(const half8*)(vp + 16);
      vh[3] = *(const half8*)(vp + 24);
      const float p = l[j];
#pragma unroll
      for (int g = 0; g < 4; ++g)
#pragma unroll
        for (int e = 0; e < 8; ++e) out[g * 8 + e] = fmaf(p, (float)vh[g][e], out[g * 8 + e]);
    }
  }

  _Float16* yp = y + (size_t)token * CDIM + cbase;
  half8 oh[4];
#pragma unroll
  for (int g = 0; g < 4; ++g) {
#pragma unroll
    for (int e = 0; e < 8; ++e) oh[g][e] = (_Float16)(out[g * 8 + e] * rs);
    *(half8*)(yp + g * 8) = oh[g];
  }
}

extern "C" void kernel_launch(void* const* d_in, const int* in_sizes, int n_in,
                              void* d_out, int out_size, void* d_ws, size_t ws_size,
                              hipStream_t stream) {
  const float* x = (const float*)d_in[0];       // [16,56,56,384]
  const float* w_qkv = (const float*)d_in[1];   // [1152,384]
  const float* w_proj = (const float*)d_in[2];  // [384,384]
  const float* b_proj = (const float*)d_in[3];  // [384]
  float* out = (float*)d_out;                   // [50176,384]

  _Float16* xh = (_Float16*)d_ws;                     // 50176*384
  _Float16* wqh = xh + (size_t)NTOK * CDIM;           // 1152*384
  _Float16* wph = wqh + (size_t)ROWQKV * CDIM;        // 384*384
  _Float16* qkvh = wph + (size_t)CDIM * CDIM;         // 50176*1152
  _Float16* yh = qkvh + (size_t)NTOK * ROWQKV;        // 50176*384

  conv_all<<<2048, 256, 0, stream>>>(x, w_qkv, w_proj, xh, wqh, wph);

  gemm3<true><<<(NTOK / 128) * (ROWQKV / 128), 256, 0, stream>>>(
      xh, wqh, nullptr, qkvh, ROWQKV, CDIM);

  attn_kernel<<<(NTOK * 12) / 256, 256, 0, stream>>>(qkvh, yh);

  gemm3<false><<<(NTOK / 128) * (CDIM / 128), 256, 0, stream>>>(
      yh, wph, b_proj, out, CDIM, CDIM);
}

// Round 10
// 187.761 us; speedup vs baseline: 1.0025x; 1.0025x over previous
//
#include <hip/hip_runtime.h>
#include <hip/hip_bf16.h>

// MultiDilatelocalAttention, round 10: 4-buffer single-barrier GEMM pipeline.
// One s_barrier per K-step (was 2): stage tile h+2 into buf (h+2)%4, gate with
// counted vmcnt(8). 4 buffers make the WAR pairing safe with a single barrier
// (stage@h+1 writes (h+3)%4; all reads of that buf finished before barrier@h).
// conv_all / attention / XCD remap unchanged.

#define NTOK 50176
#define ROWQKV 1152
#define CDIM 384

typedef _Float16 half2v __attribute__((ext_vector_type(2)));
typedef _Float16 half8 __attribute__((ext_vector_type(8)));
typedef float floatx4 __attribute__((ext_vector_type(4)));

typedef __attribute__((address_space(1))) const unsigned int GU32;
typedef __attribute__((address_space(3))) unsigned int LU32;

// ---------------- fused fp32 -> fp16 conversion: x, w_qkv, w_proj ----------------
#define N_X4 (NTOK * CDIM / 4)
#define N_Q4 (ROWQKV * CDIM / 4)
#define N_P4 (CDIM * CDIM / 4)

__global__ __launch_bounds__(256) void conv_all(const float* __restrict__ x,
                                                const float* __restrict__ wq,
                                                const float* __restrict__ wp,
                                                _Float16* __restrict__ xh,
                                                _Float16* __restrict__ wqh,
                                                _Float16* __restrict__ wph) {
  const int total = N_X4 + N_Q4 + N_P4;
  int i = blockIdx.x * 256 + threadIdx.x;
  const int stride = gridDim.x * 256;
  for (; i < total; i += stride) {
    const float* src;
    _Float16* dst;
    int k;
    if (i < N_X4) { src = x; dst = xh; k = i; }
    else if (i < N_X4 + N_Q4) { src = wq; dst = wqh; k = i - N_X4; }
    else { src = wp; dst = wph; k = i - N_X4 - N_Q4; }
    float4 v = ((const float4*)src)[k];
    union { _Float16 h[4]; uint2 u; } o;
    o.h[0] = (_Float16)v.x; o.h[1] = (_Float16)v.y;
    o.h[2] = (_Float16)v.z; o.h[3] = (_Float16)v.w;
    ((uint2*)dst)[k] = o.u;
  }
}

// ---------------- f16 MFMA GEMM, 4-buffer 1-barrier: C = A * B^T ----------------
// 128x128 tile, BK=32, 256 threads (4 waves 2x2), 4x4 frags of 16x16x32 per wave.
// Step h: stage(h+2 -> buf (h+2)%4); vmcnt(8) [h+1,h+2 in flight]; ONE barrier;
// ds_read + 16 MFMA (setprio). LDS = 4 bufs x (8KB A + 8KB B) = 64KB.
// 1D grid, XCD-chunked remap.
template <bool HALF_OUT>
__global__ __launch_bounds__(256) void gemm3(const _Float16* __restrict__ A,
                                             const _Float16* __restrict__ B,
                                             const float* __restrict__ bias,
                                             void* __restrict__ Cout,
                                             int N, int K) {
  __shared__ _Float16 As[4][128 * 32];
  __shared__ _Float16 Bs[4][128 * 32];
  const int tid = threadIdx.x;
  const int lane = tid & 63;
  const int wv = tid >> 6;
  const int wr = wv >> 1, wc = wv & 1;

  const int nN = N >> 7;
  const int p = blockIdx.x;
  const int l = (p & 7) * (gridDim.x >> 3) + (p >> 3);
  const size_t row0 = (size_t)(l / nN) * 128;
  const int col0 = (l % nN) * 128;
  const int NT = K / 32;

  const int srow = tid >> 2;
  const int gslot = (tid & 3) ^ ((srow >> 1) & 3);  // swizzled source slot
  const _Float16* Abase = A + (row0 + srow) * (size_t)K + gslot * 8;
  const _Float16* Bbase = B + ((size_t)(col0 + srow)) * (size_t)K + gslot * 8;
  char* AsB = (char*)As;
  char* BsB = (char*)Bs;

  auto stage = [&](int k0, int buf) {
    __builtin_amdgcn_global_load_lds((GU32*)(Abase + k0),
                                     (LU32*)(AsB + buf * 8192 + tid * 16), 16, 0, 0);
    __builtin_amdgcn_global_load_lds((GU32*)(Abase + (size_t)64 * K + k0),
                                     (LU32*)(AsB + buf * 8192 + tid * 16 + 4096), 16, 0, 0);
    __builtin_amdgcn_global_load_lds((GU32*)(Bbase + k0),
                                     (LU32*)(BsB + buf * 8192 + tid * 16), 16, 0, 0);
    __builtin_amdgcn_global_load_lds((GU32*)(Bbase + (size_t)64 * K + k0),
                                     (LU32*)(BsB + buf * 8192 + tid * 16 + 4096), 16, 0, 0);
  };

  const int fr = lane & 15;
  const int fq = lane >> 4;
  const int rpos = (fq ^ ((fr >> 1) & 3)) * 8;

  floatx4 acc[4][4];
#pragma unroll
  for (int i = 0; i < 4; ++i)
#pragma unroll
    for (int j = 0; j < 4; ++j) acc[i][j] = (floatx4){0.f, 0.f, 0.f, 0.f};

  // prologue: two tiles in flight, no drain
  stage(0, 0);
  stage(32, 1);

  for (int h = 0; h < NT; ++h) {
    const int cur = h & 3;
    // depth-2 prefetch: tile h+2 -> buf (h+2)%4 (WAR-safe: its last readers
    // were at step h-2, finished before barrier@h-1)
    if (h + 2 < NT) {
      stage((h + 2) * 32, (h + 2) & 3);
      asm volatile("s_waitcnt vmcnt(8)" ::: "memory");   // h+1, h+2 stay in flight
    } else if (h + 1 < NT) {
      asm volatile("s_waitcnt vmcnt(4)" ::: "memory");   // h+1 stays in flight
    } else {
      asm volatile("s_waitcnt vmcnt(0)" ::: "memory");
    }
    __builtin_amdgcn_s_barrier();          // tile h landed for ALL threads
    __builtin_amdgcn_sched_barrier(0);     // nothing crosses the barrier

    half8 af[4], bf[4];
#pragma unroll
    for (int f = 0; f < 4; ++f) {
      af[f] = *(const half8*)&As[cur][(wr * 64 + f * 16 + fr) * 32 + rpos];
      bf[f] = *(const half8*)&Bs[cur][(wc * 64 + f * 16 + fr) * 32 + rpos];
    }
    __builtin_amdgcn_s_setprio(1);
#pragma unroll
    for (int i = 0; i < 4; ++i)
#pragma unroll
      for (int j = 0; j < 4; ++j)
        acc[i][j] = __builtin_amdgcn_mfma_f32_16x16x32_f16(af[i], bf[j], acc[i][j], 0, 0, 0);
    __builtin_amdgcn_s_setprio(0);
    // no trailing barrier: next step's stage targets buf (h+4)%4 == cur only
    // after the NEXT barrier; buffers at distance 2 are never touched earlier.
  }

  const int crow = wr * 64 + (lane >> 4) * 4;
  const int ccol = wc * 64 + (lane & 15);
#pragma unroll
  for (int fm = 0; fm < 4; ++fm) {
#pragma unroll
    for (int fn = 0; fn < 4; ++fn) {
      const size_t r0 = (row0 + crow + fm * 16) * (size_t)N + col0 + ccol + fn * 16;
      if (HALF_OUT) {
        _Float16* C = (_Float16*)Cout;
#pragma unroll
        for (int j = 0; j < 4; ++j) C[r0 + (size_t)j * N] = (_Float16)acc[fm][fn][j];
      } else {
        float* C = (float*)Cout;
        const float bz = bias[col0 + ccol + fn * 16];
#pragma unroll
        for (int j = 0; j < 4; ++j) C[r0 + (size_t)j * N] = acc[fm][fn][j] + bz;
      }
    }
  }
}

// ---------------- Local attention: one thread per (token, head) ----------------
__global__ __launch_bounds__(256) void attn_kernel(const _Float16* __restrict__ qkv,
                                                   _Float16* __restrict__ y) {
  const int idx = blockIdx.x * 256 + threadIdx.x;  // token*12 + head
  const int head = idx % 12;
  const int token = idx / 12;
  const int branch = head >> 2;
  const int dil = branch + 1;
  const int cbase = branch * 128 + (head & 3) * 32;
  const int xx = token % 56;
  const int yy = (token / 56) % 56;
  const int bimg = token / 3136;
  const float scale = 0.17677669529663687f;  // 1/sqrt(32)

  const _Float16* qp = qkv + (size_t)token * ROWQKV + cbase;
  half2v qh[16];
  *(half8*)&qh[0] = *(const half8*)(qp);
  *(half8*)&qh[4] = *(const half8*)(qp + 8);
  *(half8*)&qh[8] = *(const half8*)(qp + 16);
  *(half8*)&qh[12] = *(const half8*)(qp + 24);

  const size_t nbase = (size_t)bimg * 3136;

  float l[9];
#pragma unroll
  for (int j = 0; j < 9; ++j) {
    const int ny = yy + (j / 3 - 1) * dil;
    const int nx = xx + (j % 3 - 1) * dil;
    float d = 0.f;
    if ((unsigned)ny < 56u && (unsigned)nx < 56u) {
      const _Float16* kp = qkv + (nbase + ny * 56 + nx) * ROWQKV + 384 + cbase;
      half2v kh[16];
      *(half8*)&kh[0] = *(const half8*)(kp);
      *(half8*)&kh[4] = *(const half8*)(kp + 8);
      *(half8*)&kh[8] = *(const half8*)(kp + 16);
      *(half8*)&kh[12] = *(const half8*)(kp + 24);
#if __has_builtin(__builtin_amdgcn_fdot2)
#pragma unroll
      for (int c = 0; c < 16; ++c) d = __builtin_amdgcn_fdot2(qh[c], kh[c], d, false);
#else
#pragma unroll
      for (int c = 0; c < 16; ++c)
        d += (float)qh[c][0] * (float)kh[c][0] + (float)qh[c][1] * (float)kh[c][1];
#endif
    }
    l[j] = d * scale;
  }

  float m = l[0];
#pragma unroll
  for (int j = 1; j < 9; ++j) m = fmaxf(m, l[j]);
  float s = 0.f;
#pragma unroll
  for (int j = 0; j < 9; ++j) { l[j] = expf(l[j] - m); s += l[j]; }
  const float rs = 1.f / s;

  float out[32];
#pragma unroll
  for (int c = 0; c < 32; ++c) out[c] = 0.f;
#pragma unroll
  for (int j = 0; j < 9; ++j) {
    const int ny = yy + (j / 3 - 1) * dil;
    const int nx = xx + (j % 3 - 1) * dil;
    if ((unsigned)ny < 56u && (unsigned)nx < 56u) {
      const _Float16* vp = qkv + (nbase + ny * 56 + nx) * ROWQKV + 768 + cbase;
      half8 vh[4];
      vh[0] = *(const half8*)(vp);
      vh[1] = *(const half8*)(vp + 8);
      vh[2] = *(const half8*)(vp + 16);
      vh[3] = *(const half8*)(vp + 24);
      const float p = l[j];
#pragma unroll
      for (int g = 0; g < 4; ++g)
#pragma unroll
        for (int e = 0; e < 8; ++e) out[g * 8 + e] = fmaf(p, (float)vh[g][e], out[g * 8 + e]);
    }
  }

  _Float16* yp = y + (size_t)token * CDIM + cbase;
  half8 oh[4];
#pragma unroll
  for (int g = 0; g < 4; ++g) {
#pragma unroll
    for (int e = 0; e < 8; ++e) oh[g][e] = (_Float16)(out[g * 8 + e] * rs);
    *(half8*)(yp + g * 8) = oh[g];
  }
}

extern "C" void kernel_launch(void* const* d_in, const int* in_sizes, int n_in,
                              void* d_out, int out_size, void* d_ws, size_t ws_size,
                              hipStream_t stream) {
  const float* x = (const float*)d_in[0];       // [16,56,56,384]
  const float* w_qkv = (const float*)d_in[1];   // [1152,384]
  const float* w_proj = (const float*)d_in[2];  // [384,384]
  const float* b_proj = (const float*)d_in[3];  // [384]
  float* out = (float*)d_out;                   // [50176,384]

  _Float16* xh = (_Float16*)d_ws;                     // 50176*384
  _Float16* wqh = xh + (size_t)NTOK * CDIM;           // 1152*384
  _Float16* wph = wqh + (size_t)ROWQKV * CDIM;        // 384*384
  _Float16* qkvh = wph + (size_t)CDIM * CDIM;         // 50176*1152
  _Float16* yh = qkvh + (size_t)NTOK * ROWQKV;        // 50176*384

  conv_all<<<2048, 256, 0, stream>>>(x, w_qkv, w_proj, xh, wqh, wph);

  gemm3<true><<<(NTOK / 128) * (ROWQKV / 128), 256, 0, stream>>>(
      xh, wqh, nullptr, qkvh, ROWQKV, CDIM);

  attn_kernel<<<(NTOK * 12) / 256, 256, 0, stream>>>(qkvh, yh);

  gemm3<false><<<(NTOK / 128) * (CDIM / 128), 256, 0, stream>>>(
      yh, wph, b_proj, out, CDIM, CDIM);
}

// Round 11
// 187.169 us; speedup vs baseline: 1.0057x; 1.0032x over previous
//
#include <hip/hip_runtime.h>
#include <hip/hip_bf16.h>

// MultiDilatelocalAttention, round 11:
// - QKV GEMM rebuilt on the proven 256²/8-wave/4-phase-per-K-tile template
//   (T2 swizzle + T3/T4 counted vmcnt + T5 setprio, per-phase barriers).
//   qkv padded to N=1280 so BN=256 divides; attn reads with stride 1280.
// - proj GEMM = round-8 exact (2-buf, vmcnt(4)); conv_all/attn unchanged.

#define NTOK 50176
#define ROWQKV 1152
#define NQP 1280   // padded qkv row stride
#define CDIM 384

typedef _Float16 half2v __attribute__((ext_vector_type(2)));
typedef _Float16 half8 __attribute__((ext_vector_type(8)));
typedef float floatx4 __attribute__((ext_vector_type(4)));

typedef __attribute__((address_space(1))) const unsigned int GU32;
typedef __attribute__((address_space(3))) unsigned int LU32;

// ---------------- fused fp32 -> fp16 conversion: x, w_qkv, w_proj ----------------
#define N_X4 (NTOK * CDIM / 4)
#define N_Q4 (ROWQKV * CDIM / 4)
#define N_P4 (CDIM * CDIM / 4)

__global__ __launch_bounds__(256) void conv_all(const float* __restrict__ x,
                                                const float* __restrict__ wq,
                                                const float* __restrict__ wp,
                                                _Float16* __restrict__ xh,
                                                _Float16* __restrict__ wqh,
                                                _Float16* __restrict__ wph) {
  const int total = N_X4 + N_Q4 + N_P4;
  int i = blockIdx.x * 256 + threadIdx.x;
  const int stride = gridDim.x * 256;
  for (; i < total; i += stride) {
    const float* src;
    _Float16* dst;
    int k;
    if (i < N_X4) { src = x; dst = xh; k = i; }
    else if (i < N_X4 + N_Q4) { src = wq; dst = wqh; k = i - N_X4; }
    else { src = wp; dst = wph; k = i - N_X4 - N_Q4; }
    float4 v = ((const float4*)src)[k];
    union { _Float16 h[4]; uint2 u; } o;
    o.h[0] = (_Float16)v.x; o.h[1] = (_Float16)v.y;
    o.h[2] = (_Float16)v.z; o.h[3] = (_Float16)v.w;
    ((uint2*)dst)[k] = o.u;
  }
}

// ---------------- QKV GEMM: 256x256 tile, 8 waves, 4 phases/K-tile ----------------
// C[50176][1280(pad)] = A[50176][384] * B[1280(pad)][384]^T, f16 out.
// BK=64, dbuf LDS 128KB. Per K-tile: stage(kt+1) 8x glds; gate vmcnt(8); then
// 4 phases {ds_read subtile; lgkmcnt(0); setprio(1); 16 MFMA; setprio(0); barrier}.
// 3-bit XOR granule swizzle (slot ^= row&7) on glds SOURCE and ds_read sides.
__global__ __launch_bounds__(512, 1) void gemm_qkv8(const _Float16* __restrict__ A,
                                                    const _Float16* __restrict__ B,
                                                    _Float16* __restrict__ C) {
  __shared__ _Float16 As[2][256 * 64];
  __shared__ _Float16 Bs[2][256 * 64];
  const int tid = threadIdx.x;
  const int lane = tid & 63;
  const int wv = tid >> 6;      // 0..7
  const int wr = wv >> 2;       // m-half (128 rows)
  const int wc = wv & 3;        // n-quarter (64 cols)
  const int K = CDIM;

  // bijective XCD-chunked remap (m204; gridDim=980, 980%8=4)
  const int p = blockIdx.x;
  const int xcd = p & 7, bi = p >> 3;
  const int q = gridDim.x >> 3, r = gridDim.x & 7;
  const int l = (xcd < r) ? xcd * (q + 1) + bi : r * (q + 1) + (xcd - r) * q + bi;
  const int nN = NQP / 256;     // 5
  const size_t row0 = (size_t)(l / nN) * 256;
  const int col0 = (l % nN) * 256;

  // staging: per glds call 512 thr x 16B = 64 rows of 128B
  const int sr = tid >> 3;               // 0..63
  const int ss = tid & 7;                // linear dest slot
  const int aslot = (ss ^ (sr & 7)) * 8; // swizzled SOURCE granule (f16 elems)
  char* AsB = (char*)As;
  char* BsB = (char*)Bs;

  auto stage = [&](int kt, int buf) {
    const int k0 = kt * 64;
#pragma unroll
    for (int c = 0; c < 4; ++c)
      __builtin_amdgcn_global_load_lds(
          (GU32*)(A + (row0 + c * 64 + sr) * (size_t)K + k0 + aslot),
          (LU32*)(AsB + buf * 32768 + c * 8192 + tid * 16), 16, 0, 0);
#pragma unroll
    for (int c = 0; c < 4; ++c)
      __builtin_amdgcn_global_load_lds(
          (GU32*)(B + ((size_t)(col0 + c * 64 + sr)) * K + k0 + aslot),
          (LU32*)(BsB + buf * 32768 + c * 8192 + tid * 16), 16, 0, 0);
  };

  const int fr = lane & 15;
  const int fq = lane >> 4;
  const int frm = fr & 7;

  floatx4 acc[8][4];
#pragma unroll
  for (int m = 0; m < 8; ++m)
#pragma unroll
    for (int n = 0; n < 4; ++n) acc[m][n] = (floatx4){0.f, 0.f, 0.f, 0.f};

  stage(0, 0);
  asm volatile("s_waitcnt vmcnt(0)" ::: "memory");
  __builtin_amdgcn_s_barrier();

  for (int kt = 0; kt < 6; ++kt) {
    const int buf = kt & 1;
    if (kt < 5) {
      stage(kt + 1, buf ^ 1);
      asm volatile("s_waitcnt vmcnt(8)" ::: "memory");  // kt landed; kt+1 in flight
    } else {
      asm volatile("s_waitcnt vmcnt(0)" ::: "memory");
    }
    __builtin_amdgcn_s_barrier();         // tile kt visible to all waves
    __builtin_amdgcn_sched_barrier(0);

    const char* ab = AsB + buf * 32768;
    const char* bb = BsB + buf * 32768;
    half8 af[4], bf[4];
#pragma unroll
    for (int kh = 0; kh < 2; ++kh) {
      const int ko = ((((kh << 2) | fq) ^ frm) << 4);  // swizzled 16B slot
#pragma unroll
      for (int half = 0; half < 2; ++half) {
        const int mbase = half * 4;
        if (half == 0) {
#pragma unroll
          for (int n = 0; n < 4; ++n)
            bf[n] = *(const half8*)(bb + (wc * 64 + n * 16 + fr) * 128 + ko);
        }
#pragma unroll
        for (int mg = 0; mg < 4; ++mg)
          af[mg] = *(const half8*)(ab + (wr * 128 + (mbase + mg) * 16 + fr) * 128 + ko);
        asm volatile("s_waitcnt lgkmcnt(0)" ::: "memory");
        __builtin_amdgcn_sched_barrier(0);
        __builtin_amdgcn_s_setprio(1);
#pragma unroll
        for (int mg = 0; mg < 4; ++mg)
#pragma unroll
          for (int n = 0; n < 4; ++n)
            acc[mbase + mg][n] = __builtin_amdgcn_mfma_f32_16x16x32_f16(
                af[mg], bf[n], acc[mbase + mg][n], 0, 0, 0);
        __builtin_amdgcn_s_setprio(0);
        __builtin_amdgcn_sched_barrier(0);
        __builtin_amdgcn_s_barrier();     // phase end (last one = WAR guard)
      }
    }
  }

  // epilogue: C/D layout col=lane&15, row=(lane>>4)*4+reg; C stride NQP
  const int crow0 = wr * 128 + (lane >> 4) * 4;
  const int ccol0 = wc * 64 + (lane & 15);
#pragma unroll
  for (int m = 0; m < 8; ++m) {
#pragma unroll
    for (int n = 0; n < 4; ++n) {
      const size_t r0 = (row0 + crow0 + m * 16) * (size_t)NQP + col0 + ccol0 + n * 16;
#pragma unroll
      for (int j = 0; j < 4; ++j) C[r0 + (size_t)j * NQP] = (_Float16)acc[m][n][j];
    }
  }
}

// ---------------- proj GEMM (round-8 exact): C = A * B^T, dbuf + vmcnt(4) ----------------
template <bool HALF_OUT>
__global__ __launch_bounds__(256) void gemm3(const _Float16* __restrict__ A,
                                             const _Float16* __restrict__ B,
                                             const float* __restrict__ bias,
                                             void* __restrict__ Cout,
                                             int N, int K) {
  __shared__ _Float16 Asl[2][128 * 32];
  __shared__ _Float16 Bsl[2][128 * 32];
  const int tid = threadIdx.x;
  const int lane = tid & 63;
  const int wv = tid >> 6;
  const int wr = wv >> 1, wc = wv & 1;

  const int nN = N >> 7;
  const int p = blockIdx.x;
  const int l = (p & 7) * (gridDim.x >> 3) + (p >> 3);
  const size_t row0 = (size_t)(l / nN) * 128;
  const int col0 = (l % nN) * 128;
  const int NT = K / 32;

  const int srow = tid >> 2;
  const int gslot = (tid & 3) ^ ((srow >> 1) & 3);
  const _Float16* Abase = A + (row0 + srow) * (size_t)K + gslot * 8;
  const _Float16* Bbase = B + ((size_t)(col0 + srow)) * (size_t)K + gslot * 8;
  char* AsB = (char*)Asl;
  char* BsB = (char*)Bsl;

  auto stage = [&](int k0, int buf) {
    __builtin_amdgcn_global_load_lds((GU32*)(Abase + k0),
                                     (LU32*)(AsB + buf * 8192 + tid * 16), 16, 0, 0);
    __builtin_amdgcn_global_load_lds((GU32*)(Abase + (size_t)64 * K + k0),
                                     (LU32*)(AsB + buf * 8192 + tid * 16 + 4096), 16, 0, 0);
    __builtin_amdgcn_global_load_lds((GU32*)(Bbase + k0),
                                     (LU32*)(BsB + buf * 8192 + tid * 16), 16, 0, 0);
    __builtin_amdgcn_global_load_lds((GU32*)(Bbase + (size_t)64 * K + k0),
                                     (LU32*)(BsB + buf * 8192 + tid * 16 + 4096), 16, 0, 0);
  };

  const int fr = lane & 15;
  const int fq = lane >> 4;
  const int rpos = (fq ^ ((fr >> 1) & 3)) * 8;

  floatx4 acc[4][4];
#pragma unroll
  for (int i = 0; i < 4; ++i)
#pragma unroll
    for (int j = 0; j < 4; ++j) acc[i][j] = (floatx4){0.f, 0.f, 0.f, 0.f};

  stage(0, 0);
  asm volatile("s_waitcnt vmcnt(0)" ::: "memory");
  __builtin_amdgcn_s_barrier();

  int cur = 0;
  for (int t = 0; t < NT; ++t) {
    if (t + 1 < NT) {
      stage((t + 1) * 32, cur ^ 1);
      asm volatile("s_waitcnt vmcnt(4)" ::: "memory");
    } else {
      asm volatile("s_waitcnt vmcnt(0)" ::: "memory");
    }
    __builtin_amdgcn_s_barrier();
    __builtin_amdgcn_sched_barrier(0);
    half8 af[4], bf[4];
#pragma unroll
    for (int f = 0; f < 4; ++f) {
      af[f] = *(const half8*)&Asl[cur][(wr * 64 + f * 16 + fr) * 32 + rpos];
      bf[f] = *(const half8*)&Bsl[cur][(wc * 64 + f * 16 + fr) * 32 + rpos];
    }
#pragma unroll
    for (int i = 0; i < 4; ++i)
#pragma unroll
      for (int j = 0; j < 4; ++j)
        acc[i][j] = __builtin_amdgcn_mfma_f32_16x16x32_f16(af[i], bf[j], acc[i][j], 0, 0, 0);
    __builtin_amdgcn_sched_barrier(0);
    __builtin_amdgcn_s_barrier();
    cur ^= 1;
  }

  const int crow = wr * 64 + (lane >> 4) * 4;
  const int ccol = wc * 64 + (lane & 15);
#pragma unroll
  for (int fm = 0; fm < 4; ++fm) {
#pragma unroll
    for (int fn = 0; fn < 4; ++fn) {
      const size_t r0 = (row0 + crow + fm * 16) * (size_t)N + col0 + ccol + fn * 16;
      if (HALF_OUT) {
        _Float16* Cc = (_Float16*)Cout;
#pragma unroll
        for (int j = 0; j < 4; ++j) Cc[r0 + (size_t)j * N] = (_Float16)acc[fm][fn][j];
      } else {
        float* Cc = (float*)Cout;
        const float bz = bias[col0 + ccol + fn * 16];
#pragma unroll
        for (int j = 0; j < 4; ++j) Cc[r0 + (size_t)j * N] = acc[fm][fn][j] + bz;
      }
    }
  }
}

// ---------------- Local attention: one thread per (token, head); qkv stride NQP ----------------
__global__ __launch_bounds__(256) void attn_kernel(const _Float16* __restrict__ qkv,
                                                   _Float16* __restrict__ y) {
  const int idx = blockIdx.x * 256 + threadIdx.x;  // token*12 + head
  const int head = idx % 12;
  const int token = idx / 12;
  const int branch = head >> 2;
  const int dil = branch + 1;
  const int cbase = branch * 128 + (head & 3) * 32;
  const int xx = token % 56;
  const int yy = (token / 56) % 56;
  const int bimg = token / 3136;
  const float scale = 0.17677669529663687f;  // 1/sqrt(32)

  const _Float16* qp = qkv + (size_t)token * NQP + cbase;
  half2v qh[16];
  *(half8*)&qh[0] = *(const half8*)(qp);
  *(half8*)&qh[4] = *(const half8*)(qp + 8);
  *(half8*)&qh[8] = *(const half8*)(qp + 16);
  *(half8*)&qh[12] = *(const half8*)(qp + 24);

  const size_t nbase = (size_t)bimg * 3136;

  float l[9];
#pragma unroll
  for (int j = 0; j < 9; ++j) {
    const int ny = yy + (j / 3 - 1) * dil;
    const int nx = xx + (j % 3 - 1) * dil;
    float d = 0.f;
    if ((unsigned)ny < 56u && (unsigned)nx < 56u) {
      const _Float16* kp = qkv + (nbase + ny * 56 + nx) * NQP + 384 + cbase;
      half2v kh[16];
      *(half8*)&kh[0] = *(const half8*)(kp);
      *(half8*)&kh[4] = *(const half8*)(kp + 8);
      *(half8*)&kh[8] = *(const half8*)(kp + 16);
      *(half8*)&kh[12] = *(const half8*)(kp + 24);
#if __has_builtin(__builtin_amdgcn_fdot2)
#pragma unroll
      for (int c = 0; c < 16; ++c) d = __builtin_amdgcn_fdot2(qh[c], kh[c], d, false);
#else
#pragma unroll
      for (int c = 0; c < 16; ++c)
        d += (float)qh[c][0] * (float)kh[c][0] + (float)qh[c][1] * (float)kh[c][1];
#endif
    }
    l[j] = d * scale;
  }

  float m = l[0];
#pragma unroll
  for (int j = 1; j < 9; ++j) m = fmaxf(m, l[j]);
  float s = 0.f;
#pragma unroll
  for (int j = 0; j < 9; ++j) { l[j] = expf(l[j] - m); s += l[j]; }
  const float rs = 1.f / s;

  float out[32];
#pragma unroll
  for (int c = 0; c < 32; ++c) out[c] = 0.f;
#pragma unroll
  for (int j = 0; j < 9; ++j) {
    const int ny = yy + (j / 3 - 1) * dil;
    const int nx = xx + (j % 3 - 1) * dil;
    if ((unsigned)ny < 56u && (unsigned)nx < 56u) {
      const _Float16* vp = qkv + (nbase + ny * 56 + nx) * NQP + 768 + cbase;
      half8 vh[4];
      vh[0] = *(const half8*)(vp);
      vh[1] = *(const half8*)(vp + 8);
      vh[2] = *(const half8*)(vp + 16);
      vh[3] = *(const half8*)(vp + 24);
      const float p = l[j];
#pragma unroll
      for (int g = 0; g < 4; ++g)
#pragma unroll
        for (int e = 0; e < 8; ++e) out[g * 8 + e] = fmaf(p, (float)vh[g][e], out[g * 8 + e]);
    }
  }

  _Float16* yp = y + (size_t)token * CDIM + cbase;
  half8 oh[4];
#pragma unroll
  for (int g = 0; g < 4; ++g) {
#pragma unroll
    for (int e = 0; e < 8; ++e) oh[g][e] = (_Float16)(out[g * 8 + e] * rs);
    *(half8*)(yp + g * 8) = oh[g];
  }
}

extern "C" void kernel_launch(void* const* d_in, const int* in_sizes, int n_in,
                              void* d_out, int out_size, void* d_ws, size_t ws_size,
                              hipStream_t stream) {
  const float* x = (const float*)d_in[0];       // [16,56,56,384]
  const float* w_qkv = (const float*)d_in[1];   // [1152,384]
  const float* w_proj = (const float*)d_in[2];  // [384,384]
  const float* b_proj = (const float*)d_in[3];  // [384]
  float* out = (float*)d_out;                   // [50176,384]

  _Float16* xh = (_Float16*)d_ws;                     // 50176*384
  _Float16* wqh = xh + (size_t)NTOK * CDIM;           // 1280*384 (rows 1152.. = ws garbage, fine)
  _Float16* wph = wqh + (size_t)NQP * CDIM;           // 384*384
  _Float16* qkvh = wph + (size_t)CDIM * CDIM;         // 50176*1280 (pad cols never read)
  _Float16* yh = qkvh + (size_t)NTOK * NQP;           // 50176*384

  conv_all<<<2048, 256, 0, stream>>>(x, w_qkv, w_proj, xh, wqh, wph);

  // QKV: 256² tile, grid 196*5=980, 512 threads
  gemm_qkv8<<<(NTOK / 256) * (NQP / 256), 512, 0, stream>>>(xh, wqh, qkvh);

  attn_kernel<<<(NTOK * 12) / 256, 256, 0, stream>>>(qkvh, yh);

  gemm3<false><<<(NTOK / 128) * (CDIM / 128), 256, 0, stream>>>(
      yh, wph, b_proj, out, CDIM, CDIM);
}